// Round 11
// baseline (124.362 us; speedup 1.0000x reference)
//
#include <hip/hip_runtime.h>

typedef float  f32x4 __attribute__((ext_vector_type(4)));
typedef short  s16x8 __attribute__((ext_vector_type(8)));

// LDS-only barrier (no vmcnt drain): all cross-wave data (red, hbuf) is LDS.
#define LDS_BARRIER() asm volatile("s_waitcnt lgkmcnt(0)\ns_barrier" ::: "memory")

__device__ __forceinline__ unsigned short bfb(float x) {  // f32 -> bf16 bits, RNE
  unsigned u = __builtin_bit_cast(unsigned, x);
  return (unsigned short)((u + 0x7FFFu + ((u >> 16) & 1u)) >> 16);
}
__device__ __forceinline__ float fast_sig(float x) {
  float e = __builtin_amdgcn_exp2f(x * -1.44269504f);
  return __builtin_amdgcn_rcpf(1.f + e);
}
__device__ __forceinline__ float fast_tanh(float x) {
  float e = __builtin_amdgcn_exp2f(x * 2.88539008f);
  return 1.f - 2.f * __builtin_amdgcn_rcpf(1.f + e);
}

// ---------- Phase 1: vocab tables (0..300) + weight A-frags (301..308) + sort (309) ----------
__global__ __launch_bounds__(256) void tab_kernel(
    const float* __restrict__ emb,
    const float* __restrict__ Wi, const float* __restrict__ bi,
    const float* __restrict__ Ww, const float* __restrict__ bw,
    const float* __restrict__ Wh, const float* __restrict__ Wu,
    const int* __restrict__ pmask, int* __restrict__ perm,
    float* __restrict__ xi_tab, float* __restrict__ xw_tab,
    s16x8* __restrict__ frags)
{
  if (blockIdx.x == 309) {   // counting-sort rows by length (ascending)
    __shared__ int hist[33];
    __shared__ int base2[33];
    const int tid = threadIdx.x;
    if (tid < 33) hist[tid] = 0;
    __syncthreads();
    for (int i = tid; i < 8192; i += 256) atomicAdd(&hist[pmask[i]], 1);
    __syncthreads();
    if (tid == 0) {
      int acc = 0;
      for (int l = 1; l <= 32; ++l) { base2[l] = acc; acc += hist[l]; }
    }
    __syncthreads();
    for (int i = tid; i < 8192; i += 256) {
      const int pos = atomicAdd(&base2[pmask[i]], 1);
      perm[pos] = i;
    }
    return;
  }
  if (blockIdx.x >= 301) {
    const int T = blockIdx.x - 301;      // tile 0..7
    const int lane = threadIdx.x;
    if (lane >= 64) return;
    const int a = lane & 15, s = lane >> 4;
    const float* rowp[3];
    rowp[0] = Wh + (16 * T + a) * 128;          // z tile
    rowp[1] = Wh + (128 + 16 * T + a) * 128;    // r tile
    rowp[2] = Wu + (16 * T + a) * 128;          // hu tile
    #pragma unroll
    for (int mat = 0; mat < 3; ++mat) {
      #pragma unroll
      for (int kk = 0; kk < 4; ++kk) {
        const float* src = rowp[mat] + 32 * kk + 8 * s;
        const float4 A = *(const float4*)src;
        const float4 B = *(const float4*)(src + 4);
        s16x8 v;
        v[0] = (short)bfb(A.x); v[1] = (short)bfb(A.y);
        v[2] = (short)bfb(A.z); v[3] = (short)bfb(A.w);
        v[4] = (short)bfb(B.x); v[5] = (short)bfb(B.y);
        v[6] = (short)bfb(B.z); v[7] = (short)bfb(B.w);
        frags[((mat * 8 + T) * 4 + kk) * 64 + lane] = v;
      }
    }
    return;
  }

  const int v = blockIdx.x;            // 0..300
  const int g = threadIdx.x;           // 0..255
  const float4* er = (const float4*)(emb + v * 128);

  float acc = bi[g];
  const float4* wr = (const float4*)(Wi + g * 128);
  #pragma unroll 8
  for (int j = 0; j < 32; ++j) {
    float4 e = er[j], w4 = wr[j];
    acc = fmaf(e.x, w4.x, acc); acc = fmaf(e.y, w4.y, acc);
    acc = fmaf(e.z, w4.z, acc); acc = fmaf(e.w, w4.w, acc);
  }
  float accw = 0.f;
  if (g < 128) {
    accw = bw[g];
    const float4* wr2 = (const float4*)(Ww + g * 128);
    #pragma unroll 8
    for (int j = 0; j < 32; ++j) {
      float4 e = er[j], w4 = wr2[j];
      accw = fmaf(e.x, w4.x, accw); accw = fmaf(e.y, w4.y, accw);
      accw = fmaf(e.z, w4.z, accw); accw = fmaf(e.w, w4.w, accw);
    }
  }
  __shared__ float rs[4][2], rw[2][2];
  float s = acc, q = acc * acc;
  #pragma unroll
  for (int m = 1; m < 64; m <<= 1) { s += __shfl_xor(s, m); q += __shfl_xor(q, m); }
  if ((threadIdx.x & 63) == 0) { rs[threadIdx.x >> 6][0] = s; rs[threadIdx.x >> 6][1] = q; }
  float sw_ = accw, qw_ = accw * accw;
  #pragma unroll
  for (int m = 1; m < 64; m <<= 1) { sw_ += __shfl_xor(sw_, m); qw_ += __shfl_xor(qw_, m); }
  if (g < 128 && (g & 63) == 0) { rw[g >> 6][0] = sw_; rw[g >> 6][1] = qw_; }
  __syncthreads();
  const float SH = rs[0][0] + rs[1][0] + rs[2][0] + rs[3][0];
  const float QH = rs[0][1] + rs[1][1] + rs[2][1] + rs[3][1];
  const float mH = SH * (1.f / 256.f);
  const float rH = rsqrtf(fmaxf(QH * (1.f / 256.f) - mH * mH, 0.f) + 1e-5f);
  xi_tab[v * 256 + g] = (acc - mH) * rH;
  if (g < 128) {
    const float SW = rw[0][0] + rw[1][0], QW = rw[0][1] + rw[1][1];
    const float mW = SW * (1.f / 128.f);
    const float rW = rsqrtf(fmaxf(QW * (1.f / 128.f) - mW * mW, 0.f) + 1e-5f);
    xw_tab[v * 128 + g] = (accw - mW) * rW;
  }
}

// ---------- Phase 2: recurrence. 256 blocks x 256 thr (4 waves), 32 rows = 2 groups ----------
// Per phase (ONE barrier): issue group-Y h-reads + MFMAs, then group-X finish
// (fan-in/LN/pointwise/h-write/table-reload) covers Y's MFMA latency, then Y stats.

#define READ_HB(hbv, hbufg)                                                       \
  _Pragma("unroll")                                                               \
  for (int kk = 0; kk < 4; ++kk) hbv[kk] = *(const s16x8*)((hbufg) + hoff[kk]);

#define FANIN_LOAD(rv, redg)                                                      \
  _Pragma("unroll")                                                               \
  for (int c = 0; c < 16; ++c)                                                    \
    rv[c] = *(const f32x4*)&(redg)[((c >> 2) * 4 + (c & 3)) * 64 + r * 4];

#define MFMA24(az_, ar_, au_, hbv)                                                \
  _Pragma("unroll")                                                               \
  for (int u = 0; u < 2; ++u) {                                                   \
    az_[u] = f32x4{0.f,0.f,0.f,0.f}; ar_[u] = az_[u]; au_[u] = az_[u];            \
  }                                                                               \
  _Pragma("unroll")                                                               \
  for (int kk = 0; kk < 4; ++kk) {                                                \
    _Pragma("unroll")                                                             \
    for (int u = 0; u < 2; ++u) {                                                 \
      az_[u] = __builtin_amdgcn_mfma_f32_16x16x32_bf16(wz[u][kk],  hbv[kk], az_[u], 0, 0, 0); \
      ar_[u] = __builtin_amdgcn_mfma_f32_16x16x32_bf16(wr2[u][kk], hbv[kk], ar_[u], 0, 0, 0); \
      au_[u] = __builtin_amdgcn_mfma_f32_16x16x32_bf16(wu2[u][kk], hbv[kk], au_[u], 0, 0, 0); \
    }                                                                             \
  }

#define STATS_G(az_, ar_, au_, redg)                                              \
  {                                                                               \
    float s0 = 0.f, s1 = 0.f, q0 = 0.f, q1 = 0.f, su0 = 0.f, qu0 = 0.f;           \
    _Pragma("unroll")                                                             \
    for (int u = 0; u < 2; ++u) {                                                 \
      _Pragma("unroll")                                                           \
      for (int i = 0; i < 4; ++i) {                                               \
        az_[u][i] += bz[u][i];  ar_[u][i] += br2[u][i]; au_[u][i] += bu2[u][i];   \
        if (u == 0) { s0 += az_[u][i]; q0 = fmaf(az_[u][i], az_[u][i], q0);       \
                      s1 += ar_[u][i]; q1 = fmaf(ar_[u][i], ar_[u][i], q1); }     \
        else        { s0 += az_[u][i]; q0 = fmaf(az_[u][i], az_[u][i], q0);       \
                      s1 += ar_[u][i]; q1 = fmaf(ar_[u][i], ar_[u][i], q1); }     \
        su0 += au_[u][i]; qu0 = fmaf(au_[u][i], au_[u][i], qu0);                  \
      }                                                                           \
    }                                                                             \
    *(f32x4*)&(redg)[(w * 4 + s) * 64 + r * 4] = f32x4{s0 + s1, q0 + q1, su0, qu0}; \
  }

#define FINISH_G(az_, ar_, au_, rv, xiz_, xir_, xwv_, hold_, hbufg, orow_, len_, lmax_, plTg, t_) \
  {                                                                               \
    f32x4 a0 = rv[0] + rv[1], a1 = rv[2] + rv[3];                                 \
    f32x4 a2 = rv[4] + rv[5], a3 = rv[6] + rv[7];                                 \
    f32x4 a4 = rv[8] + rv[9], a5 = rv[10] + rv[11];                               \
    f32x4 a6 = rv[12] + rv[13], a7 = rv[14] + rv[15];                             \
    const f32x4 S = ((a0 + a1) + (a2 + a3)) + ((a4 + a5) + (a6 + a7));            \
    const float mH = S[0] * (1.f / 256.f);                                        \
    const float rsH = rsqrtf(fmaxf(S[1] * (1.f / 256.f) - mH * mH, 0.f) + 1e-5f); \
    const float cH = -mH * rsH;                                                   \
    const float mU = S[2] * (1.f / 128.f);                                        \
    const float rsU = rsqrtf(fmaxf(S[3] * (1.f / 128.f) - mU * mU, 0.f) + 1e-5f); \
    const float cU = -mU * rsU;                                                   \
    f32x4 hn[2];                                                                  \
    _Pragma("unroll")                                                             \
    for (int u = 0; u < 2; ++u) {                                                 \
      _Pragma("unroll")                                                           \
      for (int i = 0; i < 4; ++i) {                                               \
        const float zg = fast_sig(xiz_[u][i] + fmaf(az_[u][i], rsH, cH));         \
        const float rg = fast_sig(xir_[u][i] + fmaf(ar_[u][i], rsH, cH));         \
        const float hu = fmaf(au_[u][i], rsU, cU);                                \
        const float hh = fast_tanh(fmaf(rg, hu, xwv_[u][i]));                     \
        hn[u][i] = fmaf(zg, hh - hold_[u][i], hold_[u][i]);                       \
      }                                                                           \
    }                                                                             \
    if ((t_) == (len_) - 1) {                                                     \
      _Pragma("unroll")                                                           \
      for (int u = 0; u < 2; ++u)                                                 \
        *(float4*)((orow_) + 16 * u) = float4{hn[u][0], hn[u][1], hn[u][2], hn[u][3]}; \
    }                                                                             \
    _Pragma("unroll")                                                             \
    for (int u = 0; u < 2; ++u) {                                                 \
      const unsigned lo  = (unsigned)bfb(hn[u][0]) | ((unsigned)bfb(hn[u][1]) << 16); \
      const unsigned hi2 = (unsigned)bfb(hn[u][2]) | ((unsigned)bfb(hn[u][3]) << 16); \
      *(uint2*)((hbufg) + hwadr[u]) = uint2{lo, hi2};                             \
      hold_[u] = hn[u];                                                           \
    }                                                                             \
    const int tn_ = ((t_) + 1 < (lmax_)) ? (t_) + 1 : (t_);                       \
    const int pn_ = (plTg)[tn_ * 16 + r];                                         \
    _Pragma("unroll")                                                             \
    for (int u = 0; u < 2; ++u) {                                                 \
      xiz_[u] = *(const f32x4*)(xi_tab + pn_ * 256 + gb0 + 16 * u);               \
      xir_[u] = *(const f32x4*)(xi_tab + pn_ * 256 + 128 + gb0 + 16 * u);         \
      xwv_[u] = *(const f32x4*)(xw_tab + pn_ * 128 + gb0 + 16 * u);               \
    }                                                                             \
  }

__global__ __launch_bounds__(256, 1) void rec_kernel(
    const int* __restrict__ paths, const int* __restrict__ pmask,
    const int* __restrict__ perm,
    const float* __restrict__ bh, const float* __restrict__ bu,
    const float* __restrict__ xi_tab, const float* __restrict__ xw_tab,
    const s16x8* __restrict__ frags,
    float* __restrict__ out)
{
  __shared__ alignas(16) unsigned char hbuf[2][4096]; // per-group h, XOR(r)-swizzled
  __shared__ alignas(16) float red[2][1024];          // per-group [(w*4+s)*64 + r*4 +i]
  __shared__ int plT[2][512];                         // per-group paths [t][r]

  const int tid  = threadIdx.x;
  const int w    = tid >> 6;
  const int lane = tid & 63;
  const int s    = lane >> 4;
  const int r    = lane & 15;
  const int base = blockIdx.x * 32;
  const int gb0  = 32 * w + 4 * s;

  s16x8 wz[2][4], wr2[2][4], wu2[2][4];
  #pragma unroll
  for (int u = 0; u < 2; ++u) {
    const int T = 2 * w + u;
    #pragma unroll
    for (int kk = 0; kk < 4; ++kk) {
      wz[u][kk]  = frags[((0 * 8 + T) * 4 + kk) * 64 + lane];
      wr2[u][kk] = frags[((1 * 8 + T) * 4 + kk) * 64 + lane];
      wu2[u][kk] = frags[((2 * 8 + T) * 4 + kk) * 64 + lane];
    }
  }
  for (int k = tid; k < 1024; k += 256)
    plT[k >> 9][((k >> 4) & 31) * 16 + (k & 15)] =
        paths[perm[base + 16 * (k >> 9) + (k & 15)] * 32 + ((k >> 4) & 31)];
  ((uint4*)hbuf)[tid] = uint4{0u, 0u, 0u, 0u};
  ((uint4*)hbuf)[256 + tid] = uint4{0u, 0u, 0u, 0u};

  const int riA  = perm[base + r];
  const int riB  = perm[base + 16 + r];
  const int lenA = pmask[riA];
  const int lenB = pmask[riB];
  const int lenA_max = __shfl(lenA, 15);   // ascending buckets
  const int lenB_max = __shfl(lenB, 15);   // lenB_max >= lenA_max

  f32x4 bz[2], br2[2], bu2[2];
  #pragma unroll
  for (int u = 0; u < 2; ++u) {
    bz[u]  = *(const f32x4*)(bh + gb0 + 16 * u);
    br2[u] = *(const f32x4*)(bh + 128 + gb0 + 16 * u);
    bu2[u] = *(const f32x4*)(bu + gb0 + 16 * u);
  }
  int hoff[4];
  #pragma unroll
  for (int kk = 0; kk < 4; ++kk)
    hoff[kk] = r * 256 + (((4 * kk + s) ^ r) << 4);
  int hwadr[2];
  #pragma unroll
  for (int u = 0; u < 2; ++u)
    hwadr[u] = r * 256 + (((4 * w + 2 * u + (s >> 1)) ^ r) << 4) + (s & 1) * 8;

  f32x4 holdA[2] = {f32x4{0.f,0.f,0.f,0.f}, f32x4{0.f,0.f,0.f,0.f}};
  f32x4 holdB[2] = {f32x4{0.f,0.f,0.f,0.f}, f32x4{0.f,0.f,0.f,0.f}};
  float* orowA = out + (size_t)riA * 256 + gb0;
  float* orowB = out + (size_t)riB * 256 + gb0;

  f32x4 azA[2], arA[2], auA[2], azB[2], arB[2], auB[2];
  f32x4 xizA[2], xirA[2], xwvA[2], xizB[2], xirB[2], xwvB[2];

  __syncthreads();   // staging complete

  { // tables t=0 for both groups
    const int pA = plT[0][r], pB = plT[1][r];
    #pragma unroll
    for (int u = 0; u < 2; ++u) {
      xizA[u] = *(const f32x4*)(xi_tab + pA * 256 + gb0 + 16 * u);
      xirA[u] = *(const f32x4*)(xi_tab + pA * 256 + 128 + gb0 + 16 * u);
      xwvA[u] = *(const f32x4*)(xw_tab + pA * 128 + gb0 + 16 * u);
      xizB[u] = *(const f32x4*)(xi_tab + pB * 256 + gb0 + 16 * u);
      xirB[u] = *(const f32x4*)(xi_tab + pB * 256 + 128 + gb0 + 16 * u);
      xwvB[u] = *(const f32x4*)(xw_tab + pB * 128 + gb0 + 16 * u);
    }
  }
  { // prologue: startA(0) = MFMA_A + STATS_A
    s16x8 hbv[4];
    READ_HB(hbv, hbuf[0]);
    MFMA24(azA, arA, auA, hbv);
    STATS_G(azA, arA, auA, red[0]);
  }
  LDS_BARRIER();

  #pragma unroll 1
  for (int t = 0; t < lenB_max; ++t) {
    const bool doA  = (t < lenA_max);
    const bool doA2 = (t + 1 < lenA_max);
    // ---------- phase 1: start B(t)  ||  finish A(t) ----------
    {
      s16x8 hbv[4];
      READ_HB(hbv, hbuf[1]);                 // 1. Y h-reads
      f32x4 rv[16];
      if (doA) FANIN_LOAD(rv, red[0]);       // 2. X fan-in loads
      MFMA24(azB, arB, auB, hbv);            // 3. Y MFMAs (wait only their lgkm slice)
      if (doA)                               // 4. X finish covers Y MFMA latency
        FINISH_G(azA, arA, auA, rv, xizA, xirA, xwvA, holdA, hbuf[0],
                 orowA, lenA, lenA_max, plT[0], t);
      STATS_G(azB, arB, auB, red[1]);        // 5. Y stats (MFMAs retired)
    }
    LDS_BARRIER();
    // ---------- phase 2: start A(t+1)  ||  finish B(t) ----------
    {
      s16x8 hbv[4];
      if (doA2) READ_HB(hbv, hbuf[0]);
      f32x4 rv[16];
      FANIN_LOAD(rv, red[1]);
      if (doA2) MFMA24(azA, arA, auA, hbv);
      FINISH_G(azB, arB, auB, rv, xizB, xirB, xwvB, holdB, hbuf[1],
               orowB, lenB, lenB_max, plT[1], t);
      if (doA2) STATS_G(azA, arA, auA, red[0]);
    }
    LDS_BARRIER();
  }
}

// ---------- Phase 3: pair rows, final LN (verified) ----------
__global__ __launch_bounds__(256) void out_kernel(
    const float* __restrict__ gamma, const float* __restrict__ beta,
    float* __restrict__ out)
{
  const int tid = threadIdx.x;
  const int lane = tid & 63;
  const int m = blockIdx.x * 4 + (tid >> 6);
  float* pa = out + (size_t)(2 * m) * 256;
  float* pb = pa + 256;
  const float oa0 = pa[lane], oa1 = pa[64 + lane];
  const float ob0 = pb[lane], ob1 = pb[64 + lane];
  float s = oa0 + oa1 + ob0 + ob1;
  float q = oa0 * oa0 + oa1 * oa1 + ob0 * ob0 + ob1 * ob1;
  #pragma unroll
  for (int msk = 1; msk < 64; msk <<= 1) { s += __shfl_xor(s, msk); q += __shfl_xor(q, msk); }
  const float mean = s * (1.f / 256.f);
  const float rstd = rsqrtf(fmaxf(q * (1.f / 256.f) - mean * mean, 0.f) + 1e-5f);
  const float g0 = gamma[lane], g1 = gamma[64 + lane], g2 = gamma[128 + lane], g3 = gamma[192 + lane];
  const float b0 = beta[lane],  b1 = beta[64 + lane],  b2 = beta[128 + lane],  b3 = beta[192 + lane];
  const float na0 = (oa0 - mean) * rstd, na1 = (oa1 - mean) * rstd;
  const float nb0 = (ob0 - mean) * rstd, nb1 = (ob1 - mean) * rstd;
  pa[lane]       = na0 * g0 + b0;
  pa[64 + lane]  = na1 * g1 + b1;
  pa[128 + lane] = nb0 * g2 + b2;
  pa[192 + lane] = nb1 * g3 + b3;
  pb[lane]       = nb0 * g0 + b0;
  pb[64 + lane]  = nb1 * g1 + b1;
  pb[128 + lane] = na0 * g2 + b2;
  pb[192 + lane] = na1 * g3 + b3;
}

extern "C" void kernel_launch(void* const* d_in, const int* in_sizes, int n_in,
                              void* d_out, int out_size, void* d_ws, size_t ws_size,
                              hipStream_t stream) {
  const int*   paths = (const int*)d_in[0];
  const int*   pmask = (const int*)d_in[1];
  const float* emb   = (const float*)d_in[2];
  const float* Wi    = (const float*)d_in[3];
  const float* bi    = (const float*)d_in[4];
  const float* Wh    = (const float*)d_in[5];
  const float* bh    = (const float*)d_in[6];
  const float* Ww    = (const float*)d_in[7];
  const float* bw    = (const float*)d_in[8];
  const float* Wu    = (const float*)d_in[9];
  const float* bu    = (const float*)d_in[10];
  const float* gamma = (const float*)d_in[11];
  const float* beta  = (const float*)d_in[12];
  float* out = (float*)d_out;

  float* xi_tab = (float*)d_ws;                          // [301][256] f32
  float* xw_tab = xi_tab + 301 * 256;                    // [301][128] f32
  s16x8* frags  = (s16x8*)((char*)d_ws + 462336);        // [3*8*4][64] s16x8 = 96 KB
  int*   perm   = (int*)((char*)d_ws + 560640);          // [8192]

  hipLaunchKernelGGL(tab_kernel, dim3(310), dim3(256), 0, stream,
                     emb, Wi, bi, Ww, bw, Wh, Wu, pmask, perm, xi_tab, xw_tab, frags);
  hipLaunchKernelGGL(rec_kernel, dim3(256), dim3(256), 0, stream,
                     paths, pmask, perm, bh, bu, xi_tab, xw_tab, frags, out);
  hipLaunchKernelGGL(out_kernel, dim3(1024), dim3(256), 0, stream, gamma, beta, out);
}